// Round 1
// baseline (346.380 us; speedup 1.0000x reference)
//
#include <hip/hip_runtime.h>
#include <stdint.h>

// ---- problem constants -----------------------------------------------------
#define N_TOK   8192
#define DIMK    1024      // D == H == 1024
#define NEXP    8
#define PADROWS 17408     // 16384 assignments + up to 8*128 padding, 128-aligned
#define MAXRT   136       // max row tiles of 128

typedef __attribute__((ext_vector_type(8))) short short8;   // 8 bf16 (4 VGPRs)
typedef __attribute__((ext_vector_type(4))) float f32x4;    // MFMA accumulator
typedef unsigned short u16;

__device__ __forceinline__ u16 f2bf(float f) {              // RNE f32->bf16
  uint32_t u = __builtin_bit_cast(uint32_t, f);
  u += 0x7fffu + ((u >> 16) & 1u);
  return (u16)(u >> 16);
}

__device__ __forceinline__ void load16_lds(const void* g, void* l) {
  __builtin_amdgcn_global_load_lds(
      (const __attribute__((address_space(1))) void*)g,
      (__attribute__((address_space(3))) void*)l, 16, 0, 0);
}

// ---- workspace layout (bytes) ----------------------------------------------
#define OFF_W1T   0u
#define OFF_W2T   16777216u
#define OFF_XP    33554432u
#define OFF_H1    69206016u
#define OFF_GIDX  104857600u
#define OFF_GVAL  104923136u
#define OFF_PTOK  104988672u
#define OFF_PGATE 105058304u
#define OFF_CTRL  105127936u
// zero region each launch: ptok + pgate + ctrl = 69632+69632+128 = 139392 B

// ---- W transpose+convert: WT[e][n][k] = bf16(W[e][k][n]) -------------------
__global__ void convw_kernel(const float* __restrict__ W1, const float* __restrict__ W2,
                             u16* __restrict__ W1T, u16* __restrict__ W2T) {
  int idx = (int)blockIdx.x * 256 + (int)threadIdx.x;   // 0 .. 2*8*1024*64
  const float* src = W1; u16* dst = W1T;
  const int half = NEXP * 1024 * 64;
  if (idx >= half) { src = W2; dst = W2T; idx -= half; }
  const int k = idx & 1023;
  const int rest = idx >> 10;
  const int n0 = (rest & 63) << 4;
  const int e = rest >> 6;
  const float* s = src + ((size_t)e << 20) + ((size_t)k << 10) + n0;
  u16* d = dst + ((size_t)e << 20) + ((size_t)n0 << 10) + k;
#pragma unroll
  for (int i = 0; i < 16; ++i) d[(size_t)i << 10] = f2bf(s[i]);
}

// ---- gating: f32 logits, top-2 (jax tie-break), softmax, histogram ---------
__global__ void gate_kernel(const float* __restrict__ x, const float* __restrict__ Wg,
                            const float* __restrict__ bg, int* __restrict__ gidx,
                            float* __restrict__ gval, int* __restrict__ counts) {
  __shared__ int hist[NEXP];
  const int tid = (int)threadIdx.x;
  if (tid < NEXP) hist[tid] = 0;
  __syncthreads();
  const int n = (int)blockIdx.x * 4 + (tid >> 6);
  const int lane = tid & 63;
  float acc[NEXP];
#pragma unroll
  for (int e = 0; e < NEXP; ++e) acc[e] = 0.f;
  const float4* xr = (const float4*)(x + ((size_t)n << 10));
#pragma unroll
  for (int j = 0; j < 4; ++j) {
    float4 xv = xr[j * 64 + lane];
#pragma unroll
    for (int e = 0; e < NEXP; ++e) {
      float4 wv = ((const float4*)(Wg + ((size_t)e << 10)))[j * 64 + lane];
      acc[e] += xv.x * wv.x + xv.y * wv.y + xv.z * wv.z + xv.w * wv.w;
    }
  }
#pragma unroll
  for (int e = 0; e < NEXP; ++e)
#pragma unroll
    for (int off = 32; off; off >>= 1) acc[e] += __shfl_xor(acc[e], off, 64);
  if (lane == 0) {
    float lg[NEXP];
#pragma unroll
    for (int e = 0; e < NEXP; ++e) lg[e] = acc[e] + bg[e];
    int e0 = 0; float v0 = lg[0];
#pragma unroll
    for (int e = 1; e < NEXP; ++e) if (lg[e] > v0) { v0 = lg[e]; e0 = e; }
    int e1 = -1; float v1 = -1e30f;
#pragma unroll
    for (int e = 0; e < NEXP; ++e) if (e != e0 && lg[e] > v1) { v1 = lg[e]; e1 = e; }
    float t = expf(v1 - v0);            // v0 >= v1
    float g0 = 1.f / (1.f + t);
    gidx[2 * n] = e0; gidx[2 * n + 1] = e1;
    gval[2 * n] = g0; gval[2 * n + 1] = t * g0;
    atomicAdd(&hist[e0], 1); atomicAdd(&hist[e1], 1);
  }
  __syncthreads();
  if (tid < NEXP && hist[tid]) atomicAdd(&counts[tid], hist[tid]);
}

// ---- scan: 128-aligned segment offsets -------------------------------------
__global__ void scan_kernel(const int* __restrict__ counts, int* __restrict__ poff) {
  if (threadIdx.x == 0) {
    int off = 0; poff[0] = 0;
    for (int e = 0; e < NEXP; ++e) { off += ((counts[e] + 127) >> 7) << 7; poff[e + 1] = off; }
  }
}

// ---- scatter assignments into expert segments ------------------------------
__global__ void scatter_kernel(const int* __restrict__ gidx, const float* __restrict__ gval,
                               const int* __restrict__ poff, int* __restrict__ cursor,
                               int* __restrict__ ptok, float* __restrict__ pgate) {
  const int n = (int)blockIdx.x * 256 + (int)threadIdx.x;
#pragma unroll
  for (int k = 0; k < 2; ++k) {
    const int e = gidx[2 * n + k];
    const int p = poff[e] + atomicAdd(&cursor[e], 1);
    ptok[p] = n;
    pgate[p] = gval[2 * n + k];
  }
}

// ---- gather x rows (permuted) -> bf16 --------------------------------------
__global__ void gather_kernel(const float* __restrict__ x, const int* __restrict__ ptok,
                              u16* __restrict__ xp) {
  const int p = (int)blockIdx.x * 4 + ((int)threadIdx.x >> 6);
  const int lane = (int)threadIdx.x & 63;
  const int tok = ptok[p];
  const float4* src = (const float4*)(x + ((size_t)tok << 10));
  ushort4* dst = (ushort4*)(xp + ((size_t)p << 10));
#pragma unroll
  for (int j = 0; j < 4; ++j) {
    float4 v = src[j * 64 + lane];
    ushort4 o; o.x = f2bf(v.x); o.y = f2bf(v.y); o.z = f2bf(v.z); o.w = f2bf(v.w);
    dst[j * 64 + lane] = o;
  }
}

// ---- grouped GEMM, 128x128 tile, BK=64, mfma_f32_16x16x32_bf16 -------------
// A: [P][1024] bf16 row-major (x_perm or h1). WT: [E][1024][1024] bf16, n-major
// (pre-transposed so both frags are contiguous-16B LDS reads).
// LDS swizzle: 16B slot s_phys = s_logical ^ (row&7); staged by permuting the
// GLOBAL source col per lane (gload_lds dest stays linear), read with same XOR.
template <int PASS>
__global__ __launch_bounds__(256, 2)
void gemm_kernel(const u16* __restrict__ A, const u16* __restrict__ WT,
                 const float* __restrict__ bias, const int* __restrict__ poff,
                 const int* __restrict__ ptok, const float* __restrict__ pgate,
                 u16* __restrict__ Hout, float* __restrict__ Out) {
  __shared__ u16 As[128 * 64];
  __shared__ u16 Bs[128 * 64];
  __shared__ int tokS[128];
  __shared__ float gateS[128];

  const int ntiles = poff[NEXP] >> 7;
  const int rt = (int)blockIdx.x >> 3;
  if (rt >= ntiles) return;
  const int ct = (int)blockIdx.x & 7;

  const int tid = (int)threadIdx.x;
  const int lane = tid & 63;
  const int wid = tid >> 6;
  const int wm = (wid >> 1) * 64;
  const int wn = (wid & 1) * 64;

  const int row0 = rt * 128;
  int e = 0;
  while (row0 >= poff[e + 1]) ++e;   // segments are 128-aligned; tile never spans

  const u16* Ab = A + ((size_t)row0 << 10);
  const u16* Bb = WT + ((size_t)e << 20) + ((size_t)(ct * 128) << 10);

  if (PASS == 2 && tid < 128) {
    tokS[tid] = ptok[row0 + tid];
    gateS[tid] = pgate[row0 + tid];
  }

  f32x4 acc[4][4] = {};

  const int r_in = lane >> 3;     // row within 8-row chunk
  const int s_phys = lane & 7;    // physical 16B slot

  for (int k0 = 0; k0 < DIMK; k0 += 64) {
#pragma unroll
    for (int i = 0; i < 4; ++i) {
      const int chunk = wid * 4 + i;            // 16 chunks x 1KB = 16KB tile
      const int row = chunk * 8 + r_in;
      const int slotL = s_phys ^ (row & 7);     // pre-swizzled source slot
      const size_t goff = ((size_t)row << 10) + (size_t)(k0 + slotL * 8);
      load16_lds(Ab + goff, As + chunk * 512);
      load16_lds(Bb + goff, Bs + chunk * 512);
    }
    __syncthreads();
#pragma unroll
    for (int kk = 0; kk < 2; ++kk) {
      short8 af[4], bg_[4];
      const int kslot = kk * 4 + (lane >> 4);
#pragma unroll
      for (int mi = 0; mi < 4; ++mi) {
        const int m = wm + mi * 16 + (lane & 15);
        af[mi] = *(const short8*)((const char*)As + m * 128 + ((kslot ^ (m & 7)) << 4));
      }
#pragma unroll
      for (int ni = 0; ni < 4; ++ni) {
        const int n = wn + ni * 16 + (lane & 15);
        bg_[ni] = *(const short8*)((const char*)Bs + n * 128 + ((kslot ^ (n & 7)) << 4));
      }
#pragma unroll
      for (int mi = 0; mi < 4; ++mi)
#pragma unroll
        for (int ni = 0; ni < 4; ++ni)
          acc[mi][ni] = __builtin_amdgcn_mfma_f32_16x16x32_bf16(af[mi], bg_[ni], acc[mi][ni], 0, 0, 0);
    }
    __syncthreads();
  }

  // epilogue: C/D layout col = lane&15, row = (lane>>4)*4 + j  [m89/m91]
  const float* bb = bias + (e << 10) + ct * 128;
  const int cbase = lane & 15;
  const int rbase = (lane >> 4) * 4;
#pragma unroll
  for (int ni = 0; ni < 4; ++ni) {
    const int col = wn + ni * 16 + cbase;
    const float bv = bb[col];
#pragma unroll
    for (int mi = 0; mi < 4; ++mi) {
      const int mb = wm + mi * 16 + rbase;
#pragma unroll
      for (int j = 0; j < 4; ++j) {
        float v = fmaxf(acc[mi][ni][j] + bv, 0.0f);
        if (PASS == 1) {
          Hout[((size_t)(row0 + mb + j) << 10) + (size_t)(ct * 128 + col)] = f2bf(v);
        } else {
          const int m = mb + j;   // pad rows: gate==0 -> adds exactly 0
          unsafeAtomicAdd(Out + ((size_t)tokS[m] << 10) + (size_t)(ct * 128 + col),
                          v * gateS[m]);
        }
      }
    }
  }
}

// ---- host-side launch ------------------------------------------------------
extern "C" void kernel_launch(void* const* d_in, const int* in_sizes, int n_in,
                              void* d_out, int out_size, void* d_ws, size_t ws_size,
                              hipStream_t stream) {
  (void)in_sizes; (void)n_in; (void)ws_size;
  const float* x  = (const float*)d_in[0];
  const float* W1 = (const float*)d_in[1];
  const float* b1 = (const float*)d_in[2];
  const float* W2 = (const float*)d_in[3];
  const float* b2 = (const float*)d_in[4];
  const float* Wg = (const float*)d_in[5];
  const float* bg = (const float*)d_in[6];
  float* out = (float*)d_out;
  char* ws = (char*)d_ws;

  u16*   W1T   = (u16*)(ws + OFF_W1T);
  u16*   W2T   = (u16*)(ws + OFF_W2T);
  u16*   xp    = (u16*)(ws + OFF_XP);
  u16*   h1    = (u16*)(ws + OFF_H1);
  int*   gidx  = (int*)(ws + OFF_GIDX);
  float* gval  = (float*)(ws + OFF_GVAL);
  int*   ptok  = (int*)(ws + OFF_PTOK);
  float* pgate = (float*)(ws + OFF_PGATE);
  int*   counts = (int*)(ws + OFF_CTRL);
  int*   cursor = counts + 8;
  int*   poff   = counts + 16;

  hipMemsetAsync(d_out, 0, (size_t)out_size * 4, stream);
  hipMemsetAsync(ws + OFF_PTOK, 0, 139392, stream);

  convw_kernel<<<4096, 256, 0, stream>>>(W1, W2, W1T, W2T);
  gate_kernel<<<N_TOK / 4, 256, 0, stream>>>(x, Wg, bg, gidx, gval, counts);
  scan_kernel<<<1, 64, 0, stream>>>(counts, poff);
  scatter_kernel<<<N_TOK / 256, 256, 0, stream>>>(gidx, gval, poff, cursor, ptok, pgate);
  gather_kernel<<<PADROWS / 4, 256, 0, stream>>>(x, ptok, xp);
  gemm_kernel<1><<<MAXRT * 8, 256, 0, stream>>>(xp, W1T, b1, poff, ptok, pgate, h1, nullptr);
  gemm_kernel<2><<<MAXRT * 8, 256, 0, stream>>>(h1, W2T, b2, poff, ptok, pgate, nullptr, out);
}

// Round 2
// 344.558 us; speedup vs baseline: 1.0053x; 1.0053x over previous
//
#include <hip/hip_runtime.h>
#include <stdint.h>

// ---- problem constants -----------------------------------------------------
#define N_TOK   8192
#define DIMK    1024      // D == H == 1024
#define NEXP    8
#define PADROWS 17408     // 16384 assignments + up to 8*128 padding, 128-aligned

typedef __attribute__((ext_vector_type(8))) short short8;   // 8 bf16 (4 VGPRs)
typedef __attribute__((ext_vector_type(4))) float f32x4;    // MFMA accumulator
typedef unsigned short u16;

__device__ __forceinline__ u16 f2bf(float f) {              // RNE f32->bf16
  uint32_t u = __builtin_bit_cast(uint32_t, f);
  u += 0x7fffu + ((u >> 16) & 1u);
  return (u16)(u >> 16);
}

__device__ __forceinline__ void load16_lds(const void* g, void* l) {
  __builtin_amdgcn_global_load_lds(
      (const __attribute__((address_space(1))) void*)g,
      (__attribute__((address_space(3))) void*)l, 16, 0, 0);
}

// ---- workspace layout (bytes) ----------------------------------------------
#define OFF_W1T   0u
#define OFF_W2T   16777216u
#define OFF_XP    33554432u
#define OFF_H1    69206016u
#define OFF_GIDX  104857600u
#define OFF_GVAL  104923136u
#define OFF_PTOK  104988672u
#define OFF_PGATE 105058304u
#define OFF_CTRL  105127936u
// zero region each launch: ptok + pgate + ctrl(128B: counts/cursor/poff/qheads)

// ---- W transpose+convert: WT[e][n][k] = bf16(W[e][k][n]) -------------------
__global__ void convw_kernel(const float* __restrict__ W1, const float* __restrict__ W2,
                             u16* __restrict__ W1T, u16* __restrict__ W2T) {
  int idx = (int)blockIdx.x * 256 + (int)threadIdx.x;
  const float* src = W1; u16* dst = W1T;
  const int half = NEXP * 1024 * 64;
  if (idx >= half) { src = W2; dst = W2T; idx -= half; }
  const int k = idx & 1023;
  const int rest = idx >> 10;
  const int n0 = (rest & 63) << 4;
  const int e = rest >> 6;
  const float* s = src + ((size_t)e << 20) + ((size_t)k << 10) + n0;
  u16* d = dst + ((size_t)e << 20) + ((size_t)n0 << 10) + k;
#pragma unroll
  for (int i = 0; i < 16; ++i) d[(size_t)i << 10] = f2bf(s[i]);
}

// ---- gating: f32 logits, top-2 (jax tie-break), softmax, histogram ---------
__global__ void gate_kernel(const float* __restrict__ x, const float* __restrict__ Wg,
                            const float* __restrict__ bg, int* __restrict__ gidx,
                            float* __restrict__ gval, int* __restrict__ counts) {
  __shared__ int hist[NEXP];
  const int tid = (int)threadIdx.x;
  if (tid < NEXP) hist[tid] = 0;
  __syncthreads();
  const int n = (int)blockIdx.x * 4 + (tid >> 6);
  const int lane = tid & 63;
  float acc[NEXP];
#pragma unroll
  for (int e = 0; e < NEXP; ++e) acc[e] = 0.f;
  const float4* xr = (const float4*)(x + ((size_t)n << 10));
#pragma unroll
  for (int j = 0; j < 4; ++j) {
    float4 xv = xr[j * 64 + lane];
#pragma unroll
    for (int e = 0; e < NEXP; ++e) {
      float4 wv = ((const float4*)(Wg + ((size_t)e << 10)))[j * 64 + lane];
      acc[e] += xv.x * wv.x + xv.y * wv.y + xv.z * wv.z + xv.w * wv.w;
    }
  }
#pragma unroll
  for (int e = 0; e < NEXP; ++e)
#pragma unroll
    for (int off = 32; off; off >>= 1) acc[e] += __shfl_xor(acc[e], off, 64);
  if (lane == 0) {
    float lg[NEXP];
#pragma unroll
    for (int e = 0; e < NEXP; ++e) lg[e] = acc[e] + bg[e];
    int e0 = 0; float v0 = lg[0];
#pragma unroll
    for (int e = 1; e < NEXP; ++e) if (lg[e] > v0) { v0 = lg[e]; e0 = e; }
    int e1 = -1; float v1 = -1e30f;
#pragma unroll
    for (int e = 0; e < NEXP; ++e) if (e != e0 && lg[e] > v1) { v1 = lg[e]; e1 = e; }
    float t = expf(v1 - v0);            // v0 >= v1
    float g0 = 1.f / (1.f + t);
    gidx[2 * n] = e0; gidx[2 * n + 1] = e1;
    gval[2 * n] = g0; gval[2 * n + 1] = t * g0;
    atomicAdd(&hist[e0], 1); atomicAdd(&hist[e1], 1);
  }
  __syncthreads();
  if (tid < NEXP && hist[tid]) atomicAdd(&counts[tid], hist[tid]);
}

// ---- scan: 128-aligned segment offsets -------------------------------------
__global__ void scan_kernel(const int* __restrict__ counts, int* __restrict__ poff) {
  if (threadIdx.x == 0) {
    int off = 0; poff[0] = 0;
    for (int e = 0; e < NEXP; ++e) { off += ((counts[e] + 127) >> 7) << 7; poff[e + 1] = off; }
  }
}

// ---- scatter assignments into expert segments ------------------------------
__global__ void scatter_kernel(const int* __restrict__ gidx, const float* __restrict__ gval,
                               const int* __restrict__ poff, int* __restrict__ cursor,
                               int* __restrict__ ptok, float* __restrict__ pgate) {
  const int n = (int)blockIdx.x * 256 + (int)threadIdx.x;
#pragma unroll
  for (int k = 0; k < 2; ++k) {
    const int e = gidx[2 * n + k];
    const int p = poff[e] + atomicAdd(&cursor[e], 1);
    ptok[p] = n;
    pgate[p] = gval[2 * n + k];
  }
}

// ---- gather x rows (permuted) -> bf16 --------------------------------------
__global__ void gather_kernel(const float* __restrict__ x, const int* __restrict__ ptok,
                              u16* __restrict__ xp) {
  const int p = (int)blockIdx.x * 4 + ((int)threadIdx.x >> 6);
  const int lane = (int)threadIdx.x & 63;
  const int tok = ptok[p];
  const float4* src = (const float4*)(x + ((size_t)tok << 10));
  ushort4* dst = (ushort4*)(xp + ((size_t)p << 10));
#pragma unroll
  for (int j = 0; j < 4; ++j) {
    float4 v = src[j * 64 + lane];
    ushort4 o; o.x = f2bf(v.x); o.y = f2bf(v.y); o.z = f2bf(v.z); o.w = f2bf(v.w);
    dst[j * 64 + lane] = o;
  }
}

// ---- grouped GEMM: persistent blocks, 128x128 tile, BK=64, 2-phase dbuf ----
// A: [P][1024] bf16 row-major. WT: [E][1024][1024] bf16, n-major.
// LDS swizzle (T2, both-sides): 16B slot s_phys = s_log ^ (row&7); staged by
// permuting the GLOBAL source slot per lane (gload_lds dest linear), read with
// the same XOR. 2-phase (T3-min): STAGE(t+1) issued BEFORE compute(t); single
// __syncthreads per K-step pays only residual load latency.
template <int PASS>
__global__ __launch_bounds__(256, 2)
void gemm_kernel(const u16* __restrict__ A, const u16* __restrict__ WT,
                 const float* __restrict__ bias, const int* __restrict__ poff,
                 const int* __restrict__ ptok, const float* __restrict__ pgate,
                 u16* __restrict__ Hout, float* __restrict__ Out,
                 int* __restrict__ qhead) {
  __shared__ u16 As[2][128 * 64];
  __shared__ u16 Bs[2][128 * 64];
  __shared__ int tokS[128];
  __shared__ float gateS[128];
  __shared__ int tileS;

  const int tid = (int)threadIdx.x;
  const int lane = tid & 63;
  const int wid = tid >> 6;
  const int wm = (wid >> 1) * 64;
  const int wn = (wid & 1) * 64;
  const int r_in = lane >> 3;     // row within 8-row chunk
  const int s_phys = lane & 7;    // physical 16B slot

  const int total = (poff[NEXP] >> 7) * 8;

  for (;;) {
    if (tid == 0) tileS = atomicAdd(qhead, 1);
    __syncthreads();                       // publish tileS; fence prev epilogue
    const int tile = tileS;
    if (tile >= total) break;
    const int rt = tile >> 3;
    const int ct = tile & 7;
    const int row0 = rt * 128;
    int e = 0;
    while (row0 >= poff[e + 1]) ++e;       // 128-aligned segments: no spanning

    const u16* Ab = A + ((size_t)row0 << 10);
    const u16* Bb = WT + ((size_t)e << 20) + ((size_t)(ct * 128) << 10);

    if (PASS == 2 && tid < 128) {
      tokS[tid] = ptok[row0 + tid];
      gateS[tid] = pgate[row0 + tid];
    }

    f32x4 acc[4][4] = {};

#define STAGE(BUF, K0)                                                         \
  {                                                                            \
    _Pragma("unroll")                                                          \
    for (int i = 0; i < 4; ++i) {                                              \
      const int chunk = wid * 4 + i;                                           \
      const int row = chunk * 8 + r_in;                                        \
      const int slotL = s_phys ^ (row & 7);                                    \
      const size_t goff = ((size_t)row << 10) + (size_t)((K0) + slotL * 8);    \
      load16_lds(Ab + goff, &As[BUF][chunk * 512]);                            \
      load16_lds(Bb + goff, &Bs[BUF][chunk * 512]);                            \
    }                                                                          \
  }

#define COMPUTE(BUF)                                                           \
  {                                                                            \
    _Pragma("unroll")                                                          \
    for (int kk = 0; kk < 2; ++kk) {                                           \
      short8 af[4], bf_[4];                                                    \
      const int kslot = kk * 4 + (lane >> 4);                                  \
      _Pragma("unroll")                                                        \
      for (int mi = 0; mi < 4; ++mi) {                                         \
        const int m = wm + mi * 16 + (lane & 15);                              \
        af[mi] = *(const short8*)((const char*)&As[BUF][0] + m * 128 +         \
                                  ((kslot ^ (m & 7)) << 4));                   \
      }                                                                        \
      _Pragma("unroll")                                                        \
      for (int ni = 0; ni < 4; ++ni) {                                         \
        const int n = wn + ni * 16 + (lane & 15);                              \
        bf_[ni] = *(const short8*)((const char*)&Bs[BUF][0] + n * 128 +        \
                                   ((kslot ^ (n & 7)) << 4));                  \
      }                                                                        \
      _Pragma("unroll")                                                        \
      for (int mi = 0; mi < 4; ++mi)                                           \
        _Pragma("unroll")                                                      \
        for (int ni = 0; ni < 4; ++ni)                                         \
          acc[mi][ni] = __builtin_amdgcn_mfma_f32_16x16x32_bf16(               \
              af[mi], bf_[ni], acc[mi][ni], 0, 0, 0);                          \
    }                                                                          \
  }

    STAGE(0, 0)
    __syncthreads();
    int cur = 0;
#pragma unroll 1
    for (int t = 0; t < 15; ++t) {
      const int nb = cur ^ 1;
      STAGE(nb, (t + 1) * 64)              // issue next tile's loads first
      COMPUTE(cur)                         // overlap compute with load flight
      __syncthreads();                     // drains vmcnt; buf nb now ready
      cur = nb;
    }
    COMPUTE(cur)                           // last K-step, nothing in flight

    // epilogue: C/D layout col = lane&15, row = (lane>>4)*4 + j  [m89/m91]
    const float* bb = bias + (e << 10) + ct * 128;
    const int cbase = lane & 15;
    const int rbase = (lane >> 4) * 4;
#pragma unroll
    for (int ni = 0; ni < 4; ++ni) {
      const int col = wn + ni * 16 + cbase;
      const float bv = bb[col];
#pragma unroll
      for (int mi = 0; mi < 4; ++mi) {
        const int mb = wm + mi * 16 + rbase;
#pragma unroll
        for (int j = 0; j < 4; ++j) {
          float v = fmaxf(acc[mi][ni][j] + bv, 0.0f);
          if (PASS == 1) {
            Hout[((size_t)(row0 + mb + j) << 10) + (size_t)(ct * 128 + col)] = f2bf(v);
          } else {
            const int m = mb + j;   // pad rows: gate==0 -> adds exactly 0
            unsafeAtomicAdd(Out + ((size_t)tokS[m] << 10) + (size_t)(ct * 128 + col),
                            v * gateS[m]);
          }
        }
      }
    }
#undef STAGE
#undef COMPUTE
  }
}

// ---- host-side launch ------------------------------------------------------
extern "C" void kernel_launch(void* const* d_in, const int* in_sizes, int n_in,
                              void* d_out, int out_size, void* d_ws, size_t ws_size,
                              hipStream_t stream) {
  (void)in_sizes; (void)n_in; (void)ws_size;
  const float* x  = (const float*)d_in[0];
  const float* W1 = (const float*)d_in[1];
  const float* b1 = (const float*)d_in[2];
  const float* W2 = (const float*)d_in[3];
  const float* b2 = (const float*)d_in[4];
  const float* Wg = (const float*)d_in[5];
  const float* bg = (const float*)d_in[6];
  float* out = (float*)d_out;
  char* ws = (char*)d_ws;

  u16*   W1T   = (u16*)(ws + OFF_W1T);
  u16*   W2T   = (u16*)(ws + OFF_W2T);
  u16*   xp    = (u16*)(ws + OFF_XP);
  u16*   h1    = (u16*)(ws + OFF_H1);
  int*   gidx  = (int*)(ws + OFF_GIDX);
  float* gval  = (float*)(ws + OFF_GVAL);
  int*   ptok  = (int*)(ws + OFF_PTOK);
  float* pgate = (float*)(ws + OFF_PGATE);
  int*   counts = (int*)(ws + OFF_CTRL);
  int*   cursor = counts + 8;
  int*   poff   = counts + 16;   // 9 ints
  int*   qh1    = counts + 25;
  int*   qh2    = counts + 26;

  hipMemsetAsync(d_out, 0, (size_t)out_size * 4, stream);
  hipMemsetAsync(ws + OFF_PTOK, 0, 139392, stream);

  convw_kernel<<<4096, 256, 0, stream>>>(W1, W2, W1T, W2T);
  gate_kernel<<<N_TOK / 4, 256, 0, stream>>>(x, Wg, bg, gidx, gval, counts);
  scan_kernel<<<1, 64, 0, stream>>>(counts, poff);
  scatter_kernel<<<N_TOK / 256, 256, 0, stream>>>(gidx, gval, poff, cursor, ptok, pgate);
  gather_kernel<<<PADROWS / 4, 256, 0, stream>>>(x, ptok, xp);
  gemm_kernel<1><<<512, 256, 0, stream>>>(xp, W1T, b1, poff, ptok, pgate, h1, nullptr, qh1);
  gemm_kernel<2><<<512, 256, 0, stream>>>(h1, W2T, b2, poff, ptok, pgate, nullptr, out, qh2);
}

// Round 3
// 323.725 us; speedup vs baseline: 1.0700x; 1.0644x over previous
//
#include <hip/hip_runtime.h>
#include <stdint.h>

// ---- problem constants -----------------------------------------------------
#define N_TOK   8192
#define DIMK    1024      // D == H == 1024
#define NEXP    8
#define PADROWS 17408     // 16384 assignments + up to 8*128 padding, 128-aligned

typedef __attribute__((ext_vector_type(8))) short short8;   // 8 bf16 (4 VGPRs)
typedef __attribute__((ext_vector_type(4))) float f32x4;    // MFMA accumulator
typedef unsigned short u16;

__device__ __forceinline__ u16 f2bf(float f) {              // RNE f32->bf16
  uint32_t u = __builtin_bit_cast(uint32_t, f);
  u += 0x7fffu + ((u >> 16) & 1u);
  return (u16)(u >> 16);
}

__device__ __forceinline__ void load16_lds(const void* g, void* l) {
  __builtin_amdgcn_global_load_lds(
      (const __attribute__((address_space(1))) void*)g,
      (__attribute__((address_space(3))) void*)l, 16, 0, 0);
}

// ---- workspace layout (bytes) ----------------------------------------------
#define OFF_W1T   0u
#define OFF_W2T   16777216u
#define OFF_XP    33554432u
#define OFF_H1    69206016u
#define OFF_GIDX  104857600u
#define OFF_GVAL  104923136u
#define OFF_PTOK  104988672u
#define OFF_PGATE 105058304u
#define OFF_CTRL  105127936u
// zero region each launch: ptok + pgate + ctrl(128B: counts/cursor/poff/qheads)

// ---- W transpose+convert via LDS tile: WT[e][n][k] = bf16(W[e][k][n]) ------
// 64x64 tiles; coalesced float4 reads, coalesced short8 writes.
__global__ void convw_kernel(const float* __restrict__ W1, const float* __restrict__ W2,
                             u16* __restrict__ W1T, u16* __restrict__ W2T) {
  __shared__ u16 tile[64][65];   // [k][n], +1 pad breaks column-read conflicts
  int b = (int)blockIdx.x;
  const float* src = W1; u16* dst = W1T;
  if (b >= 2048) { src = W2; dst = W2T; b -= 2048; }
  const int e  = b >> 8;                 // 256 tiles / expert
  const int t  = b & 255;
  const int k0 = (t >> 4) << 6;
  const int n0 = (t & 15) << 6;
  const int tid = (int)threadIdx.x;
  const int r  = tid >> 2;               // k within tile
  const int c4 = (tid & 3) << 4;         // n within tile (16 floats/thread)
  const float4* s = (const float4*)(src + ((size_t)e << 20) +
                                    ((size_t)(k0 + r) << 10) + n0 + c4);
#pragma unroll
  for (int j = 0; j < 4; ++j) {
    float4 v = s[j];
    tile[r][c4 + 4 * j + 0] = f2bf(v.x);
    tile[r][c4 + 4 * j + 1] = f2bf(v.y);
    tile[r][c4 + 4 * j + 2] = f2bf(v.z);
    tile[r][c4 + 4 * j + 3] = f2bf(v.w);
  }
  __syncthreads();
  const int on = tid >> 2;               // n within tile
  const int ok = (tid & 3) << 4;         // k chunk
  u16* d = dst + ((size_t)e << 20) + ((size_t)(n0 + on) << 10) + k0 + ok;
  short8 v0, v1;
#pragma unroll
  for (int j = 0; j < 8; ++j) {
    v0[j] = (short)tile[ok + j][on];
    v1[j] = (short)tile[ok + 8 + j][on];
  }
  *(short8*)d = v0;
  *(short8*)(d + 8) = v1;
}

// ---- gating: f32 logits, top-2 (jax tie-break), softmax, histogram ---------
__global__ void gate_kernel(const float* __restrict__ x, const float* __restrict__ Wg,
                            const float* __restrict__ bg, int* __restrict__ gidx,
                            float* __restrict__ gval, int* __restrict__ counts) {
  __shared__ int hist[NEXP];
  const int tid = (int)threadIdx.x;
  if (tid < NEXP) hist[tid] = 0;
  __syncthreads();
  const int n = (int)blockIdx.x * 4 + (tid >> 6);
  const int lane = tid & 63;
  float acc[NEXP];
#pragma unroll
  for (int e = 0; e < NEXP; ++e) acc[e] = 0.f;
  const float4* xr = (const float4*)(x + ((size_t)n << 10));
#pragma unroll
  for (int j = 0; j < 4; ++j) {
    float4 xv = xr[j * 64 + lane];
#pragma unroll
    for (int e = 0; e < NEXP; ++e) {
      float4 wv = ((const float4*)(Wg + ((size_t)e << 10)))[j * 64 + lane];
      acc[e] += xv.x * wv.x + xv.y * wv.y + xv.z * wv.z + xv.w * wv.w;
    }
  }
#pragma unroll
  for (int e = 0; e < NEXP; ++e)
#pragma unroll
    for (int off = 32; off; off >>= 1) acc[e] += __shfl_xor(acc[e], off, 64);
  if (lane == 0) {
    float lg[NEXP];
#pragma unroll
    for (int e = 0; e < NEXP; ++e) lg[e] = acc[e] + bg[e];
    int e0 = 0; float v0 = lg[0];
#pragma unroll
    for (int e = 1; e < NEXP; ++e) if (lg[e] > v0) { v0 = lg[e]; e0 = e; }
    int e1 = -1; float v1 = -1e30f;
#pragma unroll
    for (int e = 0; e < NEXP; ++e) if (e != e0 && lg[e] > v1) { v1 = lg[e]; e1 = e; }
    float t = expf(v1 - v0);            // v0 >= v1
    float g0 = 1.f / (1.f + t);
    gidx[2 * n] = e0; gidx[2 * n + 1] = e1;
    gval[2 * n] = g0; gval[2 * n + 1] = t * g0;
    atomicAdd(&hist[e0], 1); atomicAdd(&hist[e1], 1);
  }
  __syncthreads();
  if (tid < NEXP && hist[tid]) atomicAdd(&counts[tid], hist[tid]);
}

// ---- scan: 128-aligned segment offsets -------------------------------------
__global__ void scan_kernel(const int* __restrict__ counts, int* __restrict__ poff) {
  if (threadIdx.x == 0) {
    int off = 0; poff[0] = 0;
    for (int e = 0; e < NEXP; ++e) { off += ((counts[e] + 127) >> 7) << 7; poff[e + 1] = off; }
  }
}

// ---- scatter assignments into expert segments ------------------------------
__global__ void scatter_kernel(const int* __restrict__ gidx, const float* __restrict__ gval,
                               const int* __restrict__ poff, int* __restrict__ cursor,
                               int* __restrict__ ptok, float* __restrict__ pgate) {
  const int n = (int)blockIdx.x * 256 + (int)threadIdx.x;
#pragma unroll
  for (int k = 0; k < 2; ++k) {
    const int e = gidx[2 * n + k];
    const int p = poff[e] + atomicAdd(&cursor[e], 1);
    ptok[p] = n;
    pgate[p] = gval[2 * n + k];
  }
}

// ---- gather x rows (permuted) -> bf16 --------------------------------------
__global__ void gather_kernel(const float* __restrict__ x, const int* __restrict__ ptok,
                              u16* __restrict__ xp) {
  const int p = (int)blockIdx.x * 4 + ((int)threadIdx.x >> 6);
  const int lane = (int)threadIdx.x & 63;
  const int tok = ptok[p];
  const float4* src = (const float4*)(x + ((size_t)tok << 10));
  ushort4* dst = (ushort4*)(xp + ((size_t)p << 10));
#pragma unroll
  for (int j = 0; j < 4; ++j) {
    float4 v = src[j * 64 + lane];
    ushort4 o; o.x = f2bf(v.x); o.y = f2bf(v.y); o.z = f2bf(v.z); o.w = f2bf(v.w);
    dst[j * 64 + lane] = o;
  }
}

// ---- grouped GEMM: persistent blocks, 128x128 tile, BK=64 ------------------
// Pipelined 2-phase (T3+T4): K-loop FULLY UNROLLED so buffer indices are
// compile-time constants (alias analysis can then prove STAGE's LDS writes
// don't touch COMPUTE's buffer -> no compiler-inserted vmcnt(0) drain).
// Raw s_barrier + counted `s_waitcnt vmcnt(8)`: the 8 just-issued loads stay
// in flight under COMPUTE; only the previous K-step's 8 must have landed.
// LDS swizzle (T2, both-sides): 16B slot s_phys = s_log ^ (row&7); staged by
// permuting the GLOBAL source slot per lane (gload_lds dest linear), read with
// the same XOR.
template <int PASS>
__global__ __launch_bounds__(256, 2)
void gemm_kernel(const u16* __restrict__ A, const u16* __restrict__ WT,
                 const float* __restrict__ bias, const int* __restrict__ poff,
                 const int* __restrict__ ptok, const float* __restrict__ pgate,
                 u16* __restrict__ Hout, float* __restrict__ Out,
                 int* __restrict__ qhead) {
  __shared__ u16 As[2][128 * 64];
  __shared__ u16 Bs[2][128 * 64];
  __shared__ int tokS[128];
  __shared__ float gateS[128];
  __shared__ int tileS;

  const int tid = (int)threadIdx.x;
  const int lane = tid & 63;
  const int wid = tid >> 6;
  const int wm = (wid >> 1) * 64;
  const int wn = (wid & 1) * 64;
  const int r_in = lane >> 3;     // row within 8-row chunk
  const int s_phys = lane & 7;    // physical 16B slot

  const int total = (poff[NEXP] >> 7) * 8;

  for (;;) {
    if (tid == 0) tileS = atomicAdd(qhead, 1);
    __syncthreads();                       // publish tileS; fence prev epilogue
    const int tile = tileS;
    if (tile >= total) break;
    const int rt = tile >> 3;
    const int ct = tile & 7;
    const int row0 = rt * 128;
    int e = 0;
    while (row0 >= poff[e + 1]) ++e;       // 128-aligned segments: no spanning

    const u16* Ab = A + ((size_t)row0 << 10);
    const u16* Bb = WT + ((size_t)e << 20) + ((size_t)(ct * 128) << 10);

    if (PASS == 2 && tid < 128) {
      tokS[tid] = ptok[row0 + tid];
      gateS[tid] = pgate[row0 + tid];
    }

    f32x4 acc[4][4] = {};

#define STAGE(BUF, K0)                                                         \
  {                                                                            \
    _Pragma("unroll")                                                          \
    for (int i = 0; i < 4; ++i) {                                              \
      const int chunk = wid * 4 + i;                                           \
      const int row = chunk * 8 + r_in;                                        \
      const int slotL = s_phys ^ (row & 7);                                    \
      const size_t goff = ((size_t)row << 10) + (size_t)((K0) + slotL * 8);    \
      load16_lds(Ab + goff, &As[BUF][chunk * 512]);                            \
      load16_lds(Bb + goff, &Bs[BUF][chunk * 512]);                            \
    }                                                                          \
  }

#define COMPUTE(BUF)                                                           \
  {                                                                            \
    _Pragma("unroll")                                                          \
    for (int kk = 0; kk < 2; ++kk) {                                           \
      short8 af[4], bf_[4];                                                    \
      const int kslot = kk * 4 + (lane >> 4);                                  \
      _Pragma("unroll")                                                        \
      for (int mi = 0; mi < 4; ++mi) {                                         \
        const int m = wm + mi * 16 + (lane & 15);                              \
        af[mi] = *(const short8*)((const char*)&As[BUF][0] + m * 128 +         \
                                  ((kslot ^ (m & 7)) << 4));                   \
      }                                                                        \
      _Pragma("unroll")                                                        \
      for (int ni = 0; ni < 4; ++ni) {                                         \
        const int n = wn + ni * 16 + (lane & 15);                              \
        bf_[ni] = *(const short8*)((const char*)&Bs[BUF][0] + n * 128 +        \
                                   ((kslot ^ (n & 7)) << 4));                  \
      }                                                                        \
      _Pragma("unroll")                                                        \
      for (int mi = 0; mi < 4; ++mi)                                           \
        _Pragma("unroll")                                                      \
        for (int ni = 0; ni < 4; ++ni)                                         \
          acc[mi][ni] = __builtin_amdgcn_mfma_f32_16x16x32_bf16(               \
              af[mi], bf_[ni], acc[mi][ni], 0, 0, 0);                          \
    }                                                                          \
  }

    STAGE(0, 0)
#pragma unroll
    for (int t = 0; t < 16; ++t) {         // FULL unroll: const buffer indices
      if (t < 15) {
        STAGE((t + 1) & 1, (t + 1) * 64)   // issue next K-step's 8 loads
        asm volatile("s_waitcnt vmcnt(8)" ::: "memory");  // prev 8 landed
      } else {
        asm volatile("s_waitcnt vmcnt(0)" ::: "memory");
      }
      __builtin_amdgcn_s_barrier();        // all waves' buf[t&1] ready
      COMPUTE(t & 1)
      asm volatile("s_waitcnt lgkmcnt(0)" ::: "memory");
      __builtin_amdgcn_s_barrier();        // reads done; buf may be rewritten
    }

    // epilogue: C/D layout col = lane&15, row = (lane>>4)*4 + j  [m89/m91]
    const float* bb = bias + (e << 10) + ct * 128;
    const int cbase = lane & 15;
    const int rbase = (lane >> 4) * 4;
#pragma unroll
    for (int ni = 0; ni < 4; ++ni) {
      const int col = wn + ni * 16 + cbase;
      const float bv = bb[col];
#pragma unroll
      for (int mi = 0; mi < 4; ++mi) {
        const int mb = wm + mi * 16 + rbase;
#pragma unroll
        for (int j = 0; j < 4; ++j) {
          float v = fmaxf(acc[mi][ni][j] + bv, 0.0f);
          if (PASS == 1) {
            Hout[((size_t)(row0 + mb + j) << 10) + (size_t)(ct * 128 + col)] = f2bf(v);
          } else {
            const int m = mb + j;   // pad rows: gate==0 -> adds exactly 0
            unsafeAtomicAdd(Out + ((size_t)tokS[m] << 10) + (size_t)(ct * 128 + col),
                            v * gateS[m]);
          }
        }
      }
    }
#undef STAGE
#undef COMPUTE
  }
}

// ---- host-side launch ------------------------------------------------------
extern "C" void kernel_launch(void* const* d_in, const int* in_sizes, int n_in,
                              void* d_out, int out_size, void* d_ws, size_t ws_size,
                              hipStream_t stream) {
  (void)in_sizes; (void)n_in; (void)ws_size;
  const float* x  = (const float*)d_in[0];
  const float* W1 = (const float*)d_in[1];
  const float* b1 = (const float*)d_in[2];
  const float* W2 = (const float*)d_in[3];
  const float* b2 = (const float*)d_in[4];
  const float* Wg = (const float*)d_in[5];
  const float* bg = (const float*)d_in[6];
  float* out = (float*)d_out;
  char* ws = (char*)d_ws;

  u16*   W1T   = (u16*)(ws + OFF_W1T);
  u16*   W2T   = (u16*)(ws + OFF_W2T);
  u16*   xp    = (u16*)(ws + OFF_XP);
  u16*   h1    = (u16*)(ws + OFF_H1);
  int*   gidx  = (int*)(ws + OFF_GIDX);
  float* gval  = (float*)(ws + OFF_GVAL);
  int*   ptok  = (int*)(ws + OFF_PTOK);
  float* pgate = (float*)(ws + OFF_PGATE);
  int*   counts = (int*)(ws + OFF_CTRL);
  int*   cursor = counts + 8;
  int*   poff   = counts + 16;   // 9 ints
  int*   qh1    = counts + 25;
  int*   qh2    = counts + 26;

  hipMemsetAsync(d_out, 0, (size_t)out_size * 4, stream);
  hipMemsetAsync(ws + OFF_PTOK, 0, 139392, stream);

  convw_kernel<<<4096, 256, 0, stream>>>(W1, W2, W1T, W2T);
  gate_kernel<<<N_TOK / 4, 256, 0, stream>>>(x, Wg, bg, gidx, gval, counts);
  scan_kernel<<<1, 64, 0, stream>>>(counts, poff);
  scatter_kernel<<<N_TOK / 256, 256, 0, stream>>>(gidx, gval, poff, cursor, ptok, pgate);
  gather_kernel<<<PADROWS / 4, 256, 0, stream>>>(x, ptok, xp);
  gemm_kernel<1><<<512, 256, 0, stream>>>(xp, W1T, b1, poff, ptok, pgate, h1, nullptr, qh1);
  gemm_kernel<2><<<512, 256, 0, stream>>>(h1, W2T, b2, poff, ptok, pgate, nullptr, out, qh2);
}